// Round 5
// baseline (457.950 us; speedup 1.0000x reference)
//
#include <hip/hip_runtime.h>
#include <cstdint>
#include <cstddef>

#define D_MODEL 2048
#define T_SEQ   2048
#define BATCH   2
#define N_HEADS 16
#define KV_HEADS 4
#define HEAD_DIM 128
#define QKV_N   3072          // D_MODEL + 2*512
#define ROWS    (BATCH * T_SEQ) // 4096

typedef float  floatx4 __attribute__((ext_vector_type(4)));
typedef short  shortx8 __attribute__((ext_vector_type(8)));
typedef __bf16 bf16x8  __attribute__((ext_vector_type(8)));

typedef const void __attribute__((address_space(1))) gvoid_t;
typedef void __attribute__((address_space(3)))       svoid_t;

__device__ __forceinline__ floatx4 mfma16(shortx8 a, shortx8 b, floatx4 c) {
  return __builtin_amdgcn_mfma_f32_16x16x32_bf16(
      __builtin_bit_cast(bf16x8, a), __builtin_bit_cast(bf16x8, b), c, 0, 0, 0);
}

__device__ __forceinline__ unsigned short f2bf(float f) {
  union { float f; unsigned int u; } v; v.f = f;
  unsigned int u = v.u;
  u += 0x7fffu + ((u >> 16) & 1u);   // RNE
  return (unsigned short)(u >> 16);
}

// native RNE cast — compiler emits v_cvt_pk_bf16_f32 for pairs (hot paths)
__device__ __forceinline__ unsigned short f2bf_hw(float f) {
  return __builtin_bit_cast(unsigned short, (__bf16)f);
}

// ---------------- fp32 -> bf16 elementwise (x) ----------------
__global__ void cvt_x(const float* __restrict__ in, unsigned short* __restrict__ out, int n4) {
  int i = blockIdx.x * blockDim.x + threadIdx.x;
  if (i >= n4) return;
  float4 v = ((const float4*)in)[i];
  ushort4 o;
  o.x = f2bf(v.x); o.y = f2bf(v.y); o.z = f2bf(v.z); o.w = f2bf(v.w);
  ((ushort4*)out)[i] = o;
}

// ---------------- fp32 W[K][N] -> bf16 Wt[N][K] ----------------
__global__ void transpose_cvt(const float* __restrict__ W, unsigned short* __restrict__ Wt,
                              int K, int N) {
  __shared__ float tile[32][33];
  int n0 = blockIdx.x * 32, k0 = blockIdx.y * 32;
  int tx = threadIdx.x, ty = threadIdx.y;   // (32, 8)
  #pragma unroll
  for (int i = 0; i < 32; i += 8)
    tile[ty + i][tx] = W[(size_t)(k0 + ty + i) * N + n0 + tx];
  __syncthreads();
  #pragma unroll
  for (int i = 0; i < 32; i += 8)
    Wt[(size_t)(n0 + ty + i) * K + k0 + tx] = f2bf(tile[tx][ty + i]);
}

// ---------------- K slice of qkv -> k_staged [b][kvh][d8][t][8] ----------------
__global__ void build_kt(const unsigned short* __restrict__ qkv, unsigned short* __restrict__ kst) {
  int o = blockIdx.x * blockDim.x + threadIdx.x;   // (((b*4+kvh)*16+d8)*2048 + t)
  int t   = o & 2047;
  int d8  = (o >> 11) & 15;
  int kvh = (o >> 15) & 3;
  int b   = o >> 17;
  uint4 v = *(const uint4*)(qkv + (size_t)(b * T_SEQ + t) * QKV_N
                            + D_MODEL + kvh * HEAD_DIM + d8 * 8);
  *(uint4*)(kst + (size_t)o * 8) = v;
}

// ---------------- V slice of qkv -> v_staged [b][kvh][t8][d][8] ----------------
__global__ void build_vt(const unsigned short* __restrict__ qkv, unsigned short* __restrict__ vst) {
  int o = blockIdx.x * blockDim.x + threadIdx.x;   // (((b*4+kvh)*256+t8)*128 + d)
  int d   = o & 127;
  int t8  = (o >> 7) & 255;
  int kvh = (o >> 15) & 3;
  int b   = o >> 17;
  const unsigned short* src = qkv + (size_t)(b * T_SEQ + t8 * 8) * QKV_N
                              + D_MODEL + 512 + kvh * HEAD_DIM + d;
  union { unsigned short s[8]; uint4 v; } tmp;
  #pragma unroll
  for (int j = 0; j < 8; ++j) tmp.s[j] = src[(size_t)j * QKV_N];
  *(uint4*)(vst + (size_t)o * 8) = tmp.v;
}

// ---------------- 256x256 8-phase bf16 GEMM: C = A[M][K] * Bt[N][K]^T + bias ----
__global__ __launch_bounds__(512, 2) void gemm256(
    const unsigned short* __restrict__ A,
    const unsigned short* __restrict__ Bt,
    const float* __restrict__ bias,
    void* __restrict__ Cout,
    int M, int N, int K, int c_bf16)
{
  __shared__ __align__(16) unsigned short lds[65536];  // A: [0,32768), B: [32768,65536)
  const int tid  = threadIdx.x;
  const int wave = tid >> 6, lane = tid & 63;
  const int quad = lane >> 4, l16 = lane & 15;
  const int wr = wave >> 2, wc = wave & 3;        // 2 x 4 wave grid
  const int bm = blockIdx.y * 256, bn = blockIdx.x * 256;
  const int NT = K >> 6;                          // 64-wide K tiles

  const int r0 = tid >> 3;                        // row 0..63 (j=0); +64 for j=1
  const int cx = (tid & 7) ^ (r0 & 7);            // inverse swizzle of k-chunk
  const size_t K64 = (size_t)64 * K;              // 64 rows worth of elements
  const unsigned short* a_src = A  + (size_t)(bm + r0) * K + cx * 8;
  const unsigned short* b_src = Bt + (size_t)(bn + r0) * K + cx * 8;
  const int wOff = wave * 512;                    // wave-uniform LDS offset (elems)

  #define LDSA_(buf, half) (lds + (((buf) << 1) + (half)) * 8192)
  #define LDSB_(buf, half) (lds + 32768 + (((buf) << 1) + (half)) * 8192)
  #define KOFF(h, t) ((size_t)(h) * 128 * K + (size_t)(t) * 64)
  #define STAGE(srcbase, ldshalf, koff) do {                                          \
    __builtin_amdgcn_global_load_lds((gvoid_t*)((srcbase) + (koff)),                  \
        (svoid_t*)((ldshalf) + wOff), 16, 0, 0);                                      \
    __builtin_amdgcn_global_load_lds((gvoid_t*)((srcbase) + (koff) + K64),            \
        (svoid_t*)((ldshalf) + wOff + 4096), 16, 0, 0);                               \
  } while (0)

  const int rowA = (wr * 64 + l16) * 64;          // within half-tile, elems
  const int rowB = (wc * 32 + l16) * 64;
  const int xo0 = ((quad)     ^ (l16 & 7)) * 8;   // ks=0 chunk
  const int xo1 = ((4 + quad) ^ (l16 & 7)) * 8;   // ks=1 chunk

  floatx4 acc[8][4] = {};
  shortx8 Afr[4][2];
  shortx8 Bfr[4][2];

  STAGE(a_src, LDSA_(0, 0), KOFF(0, 0));
  STAGE(b_src, LDSB_(0, 0), KOFF(0, 0));
  STAGE(b_src, LDSB_(0, 1), KOFF(1, 0));
  STAGE(a_src, LDSA_(0, 1), KOFF(1, 0));
  if (NT > 1) {
    STAGE(a_src, LDSA_(1, 0), KOFF(0, 1));
    STAGE(b_src, LDSB_(1, 0), KOFF(0, 1));
    STAGE(b_src, LDSB_(1, 1), KOFF(1, 1));
  }

  for (int t = 0; t < NT; ++t) {
    const int buf = t & 1;
    unsigned short* sA0 = LDSA_(buf, 0);
    unsigned short* sA1 = LDSA_(buf, 1);
    unsigned short* sB0 = LDSB_(buf, 0);
    unsigned short* sB1 = LDSB_(buf, 1);

    // ---- phase 0: Q(0,0) ----
    if (t == NT - 1) asm volatile("s_waitcnt vmcnt(0)" ::: "memory");
    else             asm volatile("s_waitcnt vmcnt(6)" ::: "memory");
    __builtin_amdgcn_s_barrier();
    #pragma unroll
    for (int mi = 0; mi < 4; ++mi) {
      Afr[mi][0] = *(const shortx8*)(sA0 + rowA + mi * 1024 + xo0);
      Afr[mi][1] = *(const shortx8*)(sA0 + rowA + mi * 1024 + xo1);
    }
    #pragma unroll
    for (int ni = 0; ni < 2; ++ni) {
      Bfr[ni][0] = *(const shortx8*)(sB0 + rowB + ni * 1024 + xo0);
      Bfr[ni][1] = *(const shortx8*)(sB0 + rowB + ni * 1024 + xo1);
    }
    if (t + 1 < NT) STAGE(a_src, LDSA_(buf ^ 1, 1), KOFF(1, t + 1));
    asm volatile("s_waitcnt lgkmcnt(0)" ::: "memory");
    __builtin_amdgcn_s_setprio(1);
    #pragma unroll
    for (int ks = 0; ks < 2; ++ks)
      #pragma unroll
      for (int mi = 0; mi < 4; ++mi)
        #pragma unroll
        for (int ni = 0; ni < 2; ++ni)
          acc[mi][ni] = mfma16(Afr[mi][ks], Bfr[ni][ks], acc[mi][ni]);
    __builtin_amdgcn_s_setprio(0);
    __builtin_amdgcn_s_barrier();

    // ---- phase 1: Q(0,1) ----
    #pragma unroll
    for (int ni = 0; ni < 2; ++ni) {
      Bfr[2 + ni][0] = *(const shortx8*)(sB1 + rowB + ni * 1024 + xo0);
      Bfr[2 + ni][1] = *(const shortx8*)(sB1 + rowB + ni * 1024 + xo1);
    }
    if (t + 2 < NT) STAGE(a_src, LDSA_(buf, 0), KOFF(0, t + 2));
    __builtin_amdgcn_s_barrier();
    asm volatile("s_waitcnt lgkmcnt(0)" ::: "memory");
    __builtin_amdgcn_s_setprio(1);
    #pragma unroll
    for (int ks = 0; ks < 2; ++ks)
      #pragma unroll
      for (int mi = 0; mi < 4; ++mi)
        #pragma unroll
        for (int ni = 0; ni < 2; ++ni)
          acc[mi][2 + ni] = mfma16(Afr[mi][ks], Bfr[2 + ni][ks], acc[mi][2 + ni]);
    __builtin_amdgcn_s_setprio(0);
    __builtin_amdgcn_s_barrier();

    // ---- phase 2: Q(1,1) ----
    #pragma unroll
    for (int mi = 0; mi < 4; ++mi) {
      Afr[mi][0] = *(const shortx8*)(sA1 + rowA + mi * 1024 + xo0);
      Afr[mi][1] = *(const shortx8*)(sA1 + rowA + mi * 1024 + xo1);
    }
    if (t + 2 < NT) STAGE(b_src, LDSB_(buf, 0), KOFF(0, t + 2));
    __builtin_amdgcn_s_barrier();
    asm volatile("s_waitcnt lgkmcnt(0)" ::: "memory");
    __builtin_amdgcn_s_setprio(1);
    #pragma unroll
    for (int ks = 0; ks < 2; ++ks)
      #pragma unroll
      for (int mi = 0; mi < 4; ++mi)
        #pragma unroll
        for (int ni = 0; ni < 2; ++ni)
          acc[4 + mi][2 + ni] = mfma16(Afr[mi][ks], Bfr[2 + ni][ks], acc[4 + mi][2 + ni]);
    __builtin_amdgcn_s_setprio(0);
    __builtin_amdgcn_s_barrier();

    // ---- phase 3: Q(1,0) ----
    if (t + 2 < NT) STAGE(b_src, LDSB_(buf, 1), KOFF(1, t + 2));
    __builtin_amdgcn_s_barrier();
    __builtin_amdgcn_s_setprio(1);
    #pragma unroll
    for (int ks = 0; ks < 2; ++ks)
      #pragma unroll
      for (int mi = 0; mi < 4; ++mi)
        #pragma unroll
        for (int ni = 0; ni < 2; ++ni)
          acc[4 + mi][ni] = mfma16(Afr[mi][ks], Bfr[ni][ks], acc[4 + mi][ni]);
    __builtin_amdgcn_s_setprio(0);
    __builtin_amdgcn_s_barrier();
  }

  #pragma unroll
  for (int mi = 0; mi < 8; ++mi) {
    const int row = bm + (mi >> 2) * 128 + wr * 64 + (mi & 3) * 16 + quad * 4;
    #pragma unroll
    for (int ni = 0; ni < 4; ++ni) {
      const int col = bn + (ni >> 1) * 128 + wc * 32 + (ni & 1) * 16 + l16;
      const float bv = bias[col];
      #pragma unroll
      for (int r = 0; r < 4; ++r) {
        float v = acc[mi][ni][r] + bv;
        if (c_bf16)
          ((unsigned short*)Cout)[(size_t)(row + r) * N + col] = f2bf_hw(v);
        else
          ((float*)Cout)[(size_t)(row + r) * N + col] = v;
      }
    }
  }
  #undef LDSA_
  #undef LDSB_
  #undef KOFF
  #undef STAGE
}

// ---------------- flash attention, GQA, causal — split-K + reg-staged prefetch --
// grid (16, N_HEADS, B) = 512 blocks x 512 threads (8 waves).
// wave = (split s = wave>>2, rowgroup g = wave&3). Q-tile pair (31-bx, bx),
// 17 lockstep iterations. T14 async-STAGE: next tile's K/V preloaded into
// 32 VGPR/thread one iteration ahead; per iter: barrier -> ds_write (vmcnt wait
// covered by full-iteration-old loads) -> issue loads for j+2 -> lgkm+barrier
// -> compute. No vmcnt drain on the critical path. Defer-max check is per-lane
// (cheap); full shuffle-reduce + rescale only in rare trigger branch.
// 73728 B LDS -> 2 blocks/CU = 16 waves/CU = 4 waves/SIMD.
__global__ __launch_bounds__(512, 4) void attn_kernel(
    const unsigned short* __restrict__ qkv,   // (B*T, 3072) bf16 (for Q)
    const unsigned short* __restrict__ kst,   // [b][kvh][d8][t][8]
    const unsigned short* __restrict__ vst,   // [b][kvh][t8][d][8]
    unsigned short* __restrict__ aout)        // (B*T, D_MODEL) bf16
{
  __shared__ __align__(16) unsigned short sK[2][16 * 64 * 8];   // per split [d8][key][8]
  __shared__ __align__(16) unsigned short sV[2][8 * 128 * 8];   // per split [t8][d][8]
  __shared__ __align__(16) unsigned short sP[8][4 * 16 * 8];    // per wave, half-P

  const int tid  = threadIdx.x;
  const int wave = tid >> 6, lane = tid & 63;
  const int split = wave >> 2, g = wave & 3;
  const int quad = lane >> 4, l16 = lane & 15;
  const int head = blockIdx.y, b = blockIdx.z;
  const int kvh = head >> 2;
  const float cf = 0.08838834764831845f * 1.4426950408889634f;  // scale*log2e
  const float THR = 25.0f;  // defer-max threshold (raw S units): P <= 2^(25*cf) ~ 9.1

  const unsigned short* kbase = kst + (size_t)((b * KV_HEADS + kvh) * 16) * 2048 * 8;
  const unsigned short* vbase = vst + (size_t)((b * KV_HEADS + kvh) * 256) * 128 * 8;
  unsigned short* sPw = sP[wave];

  // merge scratch overlays K/V LDS (only used after the kt loop, post-barrier)
  float* mrgO  = (float*)&sK[0][0];   // [g][row16][col128] f32 = 32 KB
  float* mrgML = (float*)&sV[0][0];   // [g][lane][r][{m,l}] f32 = 8 KB

  uint4 rgK[4], rgV[4];   // reg-staged next K/V tile (this split's share)

  // issue global->reg loads for tile at key-base kb_ (4x16B K + 4x16B V)
  #define LOADREGS(kb_) do {                                                   \
    _Pragma("unroll")                                                          \
    for (int it_ = 0; it_ < 4; ++it_) {                                        \
      const int c_ = it_ * 4 + g;                                              \
      rgK[it_] = *(const uint4*)(kbase + ((size_t)c_ * 2048 + (kb_)) * 8 + lane * 8); \
    }                                                                          \
    const unsigned short* vt_ = vbase + (size_t)((kb_) >> 3) * 128 * 8;        \
    _Pragma("unroll")                                                          \
    for (int it_ = 0; it_ < 4; ++it_) {                                        \
      const int c_ = it_ * 4 + g;                                              \
      rgV[it_] = *(const uint4*)(vt_ + c_ * 512 + lane * 8);                   \
    }                                                                          \
  } while (0)

  #pragma unroll 1
  for (int half = 0; half < 2; ++half) {
    const int qt = half ? blockIdx.x : (31 - blockIdx.x);
    const int q0 = qt * 64;

    // Q fragments (rowgroup g rows; both splits load the same rows)
    shortx8 qf[4];
    {
      const unsigned short* qp = qkv + (size_t)(b * T_SEQ + q0 + g * 16 + l16) * QKV_N
                                 + head * HEAD_DIM + quad * 8;
      #pragma unroll
      for (int ks = 0; ks < 4; ++ks)
        qf[ks] = *(const shortx8*)(qp + ks * 32);
    }

    float m_i[4], l_i[4];
    #pragma unroll
    for (int r = 0; r < 4; ++r) { m_i[r] = -__builtin_inff(); l_i[r] = 0.f; }
    floatx4 o_acc[8] = {};

    // prologue: preload tile 0 of this split (kt0 = split) into registers
    if (split <= qt) LOADREGS(split * 64);

    const int J = (qt >> 1) + 1;   // ceil((qt+1)/2)
    for (int j = 0; j < J; ++j) {
      const int kt = 2 * j + split;
      const bool act = (kt <= qt);

      __builtin_amdgcn_s_barrier();   // prev iteration's LDS reads complete
      if (act) {
        // LDS-write the reg-staged tile (vmcnt wait: loads are an iteration old)
        #pragma unroll
        for (int it = 0; it < 4; ++it) {
          const int c = it * 4 + g;
          *(uint4*)&sK[split][c * 512 + lane * 8] = rgK[it];
          *(uint4*)&sV[split][c * 512 + lane * 8] = rgV[it];
        }
      }
      // prefetch tile j+1 of this split into the just-freed registers
      { const int ktn = kt + 2; if (ktn <= qt) LOADREGS(ktn * 64); }
      asm volatile("s_waitcnt lgkmcnt(0)" ::: "memory");
      __builtin_amdgcn_s_barrier();   // tile visible to the split's 4 waves

      if (act) {
        // S = Q K^T for this wave's 16 rows x 64 keys
        floatx4 s[4] = {};
        __builtin_amdgcn_s_setprio(1);
        #pragma unroll
        for (int ks = 0; ks < 4; ++ks) {
          #pragma unroll
          for (int ct = 0; ct < 4; ++ct) {
            shortx8 kf = *(const shortx8*)&sK[split][((ks * 4 + quad) * 64 + ct * 16 + l16) * 8];
            s[ct] = mfma16(qf[ks], kf, s[ct]);
          }
        }
        __builtin_amdgcn_s_setprio(0);

        // causal mask only on the diagonal tile (wave-uniform branch)
        if (kt == qt) {
          const int qrow = q0 + g * 16 + quad * 4;
          const int kb = kt * 64;
          #pragma unroll
          for (int ct = 0; ct < 4; ++ct) {
            const int kcol = kb + ct * 16 + l16;
            #pragma unroll
            for (int r = 0; r < 4; ++r)
              if (kcol > qrow + r) s[ct][r] = -__builtin_inff();
          }
        }

        // cheap defer-max check: per-lane 4-value max vs m_i + THR, one ballot.
        // Full 16-lane reduce + rescale only in the (rare) trigger branch.
        float lmx[4];
        bool over = false;
        #pragma unroll
        for (int r = 0; r < 4; ++r) {
          lmx[r] = fmaxf(fmaxf(s[0][r], s[1][r]), fmaxf(s[2][r], s[3][r]));
          over = over || (lmx[r] > m_i[r] + THR);
        }
        if (__ballot(over)) {
          float alpha_r[4];
          #pragma unroll
          for (int r = 0; r < 4; ++r) {
            float m = lmx[r];
            m = fmaxf(m, __shfl_xor(m, 1));
            m = fmaxf(m, __shfl_xor(m, 2));
            m = fmaxf(m, __shfl_xor(m, 4));
            m = fmaxf(m, __shfl_xor(m, 8));
            const float newm = fmaxf(m_i[r], m);
            alpha_r[r] = exp2f((m_i[r] - newm) * cf);
            m_i[r] = newm;
            l_i[r] *= alpha_r[r];
          }
          #pragma unroll
          for (int nt = 0; nt < 8; ++nt)
            #pragma unroll
            for (int r = 0; r < 4; ++r) o_acc[nt][r] *= alpha_r[r];
        }

        // P = exp2((S - m)*cf); per-lane partial l
        #pragma unroll
        for (int r = 0; r < 4; ++r) {
          const float nmc = m_i[r] * cf;
          float p0 = exp2f(fmaf(s[0][r], cf, -nmc));
          float p1 = exp2f(fmaf(s[1][r], cf, -nmc));
          float p2 = exp2f(fmaf(s[2][r], cf, -nmc));
          float p3 = exp2f(fmaf(s[3][r], cf, -nmc));
          s[0][r] = p0; s[1][r] = p1; s[2][r] = p2; s[3][r] = p3;
          l_i[r] += (p0 + p1) + (p2 + p3);
        }

        // O += P V, two k-phases through a 1 KB per-wave sP
        #pragma unroll
        for (int c = 0; c < 2; ++c) {
          #pragma unroll
          for (int ctl = 0; ctl < 2; ++ctl) {
            const int ct = c * 2 + ctl;
            #pragma unroll
            for (int r = 0; r < 4; ++r)
              sPw[((ctl * 2 + (l16 >> 3)) * 16 + quad * 4 + r) * 8 + (l16 & 7)] =
                  f2bf_hw(s[ct][r]);
          }
          __asm__ __volatile__("s_waitcnt lgkmcnt(0)" ::: "memory");
          shortx8 pf = *(const shortx8*)&sPw[(quad * 16 + l16) * 8];
          __builtin_amdgcn_s_setprio(1);
          #pragma unroll
          for (int nt = 0; nt < 8; ++nt) {
            shortx8 vf = *(const shortx8*)&sV[split][((c * 4 + quad) * 128 + nt * 16 + l16) * 8];
            o_acc[nt] = mfma16(pf, vf, o_acc[nt]);
          }
          __builtin_amdgcn_s_setprio(0);
        }
      }
    }

    // ---- merge split partials, then epilogue (split0 finalizes) ----
    __builtin_amdgcn_s_barrier();   // all compute reads of K/V LDS done
    if (split == 1) {
      #pragma unroll
      for (int nt = 0; nt < 8; ++nt)
        #pragma unroll
        for (int r = 0; r < 4; ++r)
          mrgO[g * 2048 + (quad * 4 + r) * 128 + nt * 16 + l16] = o_acc[nt][r];
      #pragma unroll
      for (int r = 0; r < 4; ++r) {
        mrgML[(g * 64 + lane) * 8 + r * 2]     = m_i[r];
        mrgML[(g * 64 + lane) * 8 + r * 2 + 1] = l_i[r];
      }
    }
    asm volatile("s_waitcnt lgkmcnt(0)" ::: "memory");
    __builtin_amdgcn_s_barrier();   // partials visible

    if (split == 0) {
      float lm[4], a0[4], a1[4];
      #pragma unroll
      for (int r = 0; r < 4; ++r) {
        const float m1 = mrgML[(g * 64 + lane) * 8 + r * 2];
        const float l1 = mrgML[(g * 64 + lane) * 8 + r * 2 + 1];
        const float M = fmaxf(m_i[r], m1);
        a0[r] = exp2f((m_i[r] - M) * cf);
        a1[r] = exp2f((m1 - M) * cf);
        lm[r] = a0[r] * l_i[r] + a1[r] * l1;
      }
      #pragma unroll
      for (int nt = 0; nt < 8; ++nt)
        #pragma unroll
        for (int r = 0; r < 4; ++r)
          o_acc[nt][r] = a0[r] * o_acc[nt][r]
                       + a1[r] * mrgO[g * 2048 + (quad * 4 + r) * 128 + nt * 16 + l16];

      const int trow = q0 + g * 16 + quad * 4;
      #pragma unroll
      for (int r = 0; r < 4; ++r) {
        float l = lm[r];
        l += __shfl_xor(l, 1);
        l += __shfl_xor(l, 2);
        l += __shfl_xor(l, 4);
        l += __shfl_xor(l, 8);
        const float inv = 1.f / l;
        #pragma unroll
        for (int nt = 0; nt < 8; ++nt) {
          aout[(size_t)(b * T_SEQ + trow + r) * D_MODEL + head * HEAD_DIM + nt * 16 + l16] =
              f2bf_hw(o_acc[nt][r] * inv);
        }
      }
    }
  }
  #undef LOADREGS
}

extern "C" void kernel_launch(void* const* d_in, const int* in_sizes, int n_in,
                              void* d_out, int out_size, void* d_ws, size_t ws_size,
                              hipStream_t stream) {
  const float* x      = (const float*)d_in[0];
  // d_in[1] = attn_mask (causal; unused)
  const float* qkv_w  = (const float*)d_in[2];
  const float* qkv_b  = (const float*)d_in[3];
  const float* proj_w = (const float*)d_in[4];
  const float* proj_b = (const float*)d_in[5];
  float* out = (float*)d_out;

  char* ws = (char*)d_ws;
  unsigned short* x_bf    = (unsigned short*)(ws);
  unsigned short* qkvw_t  = (unsigned short*)(ws + (size_t)16777216);
  unsigned short* projw_t = (unsigned short*)(ws + (size_t)29360128);
  unsigned short* qkvbuf  = (unsigned short*)(ws + (size_t)37748736);
  unsigned short* vstaged = (unsigned short*)(ws + (size_t)62914560);
  unsigned short* kstaged = qkvw_t;  // safe alias: qkvw_t dead after GEMM1
  unsigned short* attn_out = x_bf;   // safe alias: x_bf dead after GEMM1

  cvt_x<<<(ROWS * D_MODEL / 4 + 255) / 256, 256, 0, stream>>>(x, x_bf, ROWS * D_MODEL / 4);
  transpose_cvt<<<dim3(QKV_N / 32, D_MODEL / 32), dim3(32, 8), 0, stream>>>(qkv_w, qkvw_t, D_MODEL, QKV_N);
  transpose_cvt<<<dim3(D_MODEL / 32, D_MODEL / 32), dim3(32, 8), 0, stream>>>(proj_w, projw_t, D_MODEL, D_MODEL);
  gemm256<<<dim3(QKV_N / 256, ROWS / 256), 512, 0, stream>>>(
      x_bf, qkvw_t, qkv_b, (void*)qkvbuf, ROWS, QKV_N, D_MODEL, 1);
  build_kt<<<1024, 256, 0, stream>>>(qkvbuf, kstaged);
  build_vt<<<1024, 256, 0, stream>>>(qkvbuf, vstaged);
  attn_kernel<<<dim3(16, N_HEADS, BATCH), 512, 0, stream>>>(qkvbuf, kstaged, vstaged, attn_out);
  gemm256<<<dim3(D_MODEL / 256, ROWS / 256), 512, 0, stream>>>(
      attn_out, projw_t, proj_b, (void*)out, ROWS, D_MODEL, D_MODEL, 0);
}

// Round 6
// 311.534 us; speedup vs baseline: 1.4700x; 1.4700x over previous
//
#include <hip/hip_runtime.h>
#include <cstdint>
#include <cstddef>

#define D_MODEL 2048
#define T_SEQ   2048
#define BATCH   2
#define N_HEADS 16
#define KV_HEADS 4
#define HEAD_DIM 128
#define QKV_N   3072          // D_MODEL + 2*512
#define ROWS    (BATCH * T_SEQ) // 4096

typedef float  floatx4 __attribute__((ext_vector_type(4)));
typedef short  shortx8 __attribute__((ext_vector_type(8)));
typedef __bf16 bf16x8  __attribute__((ext_vector_type(8)));

typedef const void __attribute__((address_space(1))) gvoid_t;
typedef void __attribute__((address_space(3)))       svoid_t;

__device__ __forceinline__ floatx4 mfma16(shortx8 a, shortx8 b, floatx4 c) {
  return __builtin_amdgcn_mfma_f32_16x16x32_bf16(
      __builtin_bit_cast(bf16x8, a), __builtin_bit_cast(bf16x8, b), c, 0, 0, 0);
}

__device__ __forceinline__ unsigned short f2bf(float f) {
  union { float f; unsigned int u; } v; v.f = f;
  unsigned int u = v.u;
  u += 0x7fffu + ((u >> 16) & 1u);   // RNE
  return (unsigned short)(u >> 16);
}

// native RNE cast — compiler emits v_cvt_pk_bf16_f32 for pairs (hot paths)
__device__ __forceinline__ unsigned short f2bf_hw(float f) {
  return __builtin_bit_cast(unsigned short, (__bf16)f);
}

// ---------------- fp32 -> bf16 elementwise (x) ----------------
__global__ void cvt_x(const float* __restrict__ in, unsigned short* __restrict__ out, int n4) {
  int i = blockIdx.x * blockDim.x + threadIdx.x;
  if (i >= n4) return;
  float4 v = ((const float4*)in)[i];
  ushort4 o;
  o.x = f2bf(v.x); o.y = f2bf(v.y); o.z = f2bf(v.z); o.w = f2bf(v.w);
  ((ushort4*)out)[i] = o;
}

// ---------------- fp32 W[K][N] -> bf16 Wt[N][K] ----------------
__global__ void transpose_cvt(const float* __restrict__ W, unsigned short* __restrict__ Wt,
                              int K, int N) {
  __shared__ float tile[32][33];
  int n0 = blockIdx.x * 32, k0 = blockIdx.y * 32;
  int tx = threadIdx.x, ty = threadIdx.y;   // (32, 8)
  #pragma unroll
  for (int i = 0; i < 32; i += 8)
    tile[ty + i][tx] = W[(size_t)(k0 + ty + i) * N + n0 + tx];
  __syncthreads();
  #pragma unroll
  for (int i = 0; i < 32; i += 8)
    Wt[(size_t)(n0 + ty + i) * K + k0 + tx] = f2bf(tile[tx][ty + i]);
}

// ---------------- K slice of qkv -> k_staged [b][kvh][d8][t][8] ----------------
__global__ void build_kt(const unsigned short* __restrict__ qkv, unsigned short* __restrict__ kst) {
  int o = blockIdx.x * blockDim.x + threadIdx.x;   // (((b*4+kvh)*16+d8)*2048 + t)
  int t   = o & 2047;
  int d8  = (o >> 11) & 15;
  int kvh = (o >> 15) & 3;
  int b   = o >> 17;
  uint4 v = *(const uint4*)(qkv + (size_t)(b * T_SEQ + t) * QKV_N
                            + D_MODEL + kvh * HEAD_DIM + d8 * 8);
  *(uint4*)(kst + (size_t)o * 8) = v;
}

// ---------------- V slice of qkv -> v_staged [b][kvh][t8][d][8] ----------------
__global__ void build_vt(const unsigned short* __restrict__ qkv, unsigned short* __restrict__ vst) {
  int o = blockIdx.x * blockDim.x + threadIdx.x;   // (((b*4+kvh)*256+t8)*128 + d)
  int d   = o & 127;
  int t8  = (o >> 7) & 255;
  int kvh = (o >> 15) & 3;
  int b   = o >> 17;
  const unsigned short* src = qkv + (size_t)(b * T_SEQ + t8 * 8) * QKV_N
                              + D_MODEL + 512 + kvh * HEAD_DIM + d;
  union { unsigned short s[8]; uint4 v; } tmp;
  #pragma unroll
  for (int j = 0; j < 8; ++j) tmp.s[j] = src[(size_t)j * QKV_N];
  *(uint4*)(vst + (size_t)o * 8) = tmp.v;
}

// ------- 256-row x (NB*128)-col 8-phase bf16 GEMM: C = A * Bt^T + bias ---------
// NB = B-fragments per half-tile per wave. NB=2: BN=256 (original, LDS 128K,
// vmcnt(6)); NB=1: BN=128 (LDS 96K, vmcnt(4)) -> 2x the blocks for narrow N.
template<int NB>
__global__ __launch_bounds__(512, 2) void gemm256(
    const unsigned short* __restrict__ A,
    const unsigned short* __restrict__ Bt,
    const float* __restrict__ bias,
    void* __restrict__ Cout,
    int M, int N, int K, int c_bf16)
{
  __shared__ __align__(16) unsigned short lds[32768 + NB * 16384];
  const int tid  = threadIdx.x;
  const int wave = tid >> 6, lane = tid & 63;
  const int quad = lane >> 4, l16 = lane & 15;
  const int wr = wave >> 2, wc = wave & 3;        // 2 x 4 wave grid
  const int bm = blockIdx.y * 256, bn = blockIdx.x * (NB * 128);
  const int NT = K >> 6;                          // 64-wide K tiles

  const int r0 = tid >> 3;                        // row 0..63 (j=0)
  const int cx = (tid & 7) ^ (r0 & 7);            // inverse swizzle of k-chunk
  const size_t K64 = (size_t)64 * K;              // 64 rows worth of elements
  const unsigned short* a_src = A  + (size_t)(bm + r0) * K + cx * 8;
  const unsigned short* b_src = Bt + (size_t)(bn + r0) * K + cx * 8;
  const int wOff = wave * 512;                    // wave-uniform LDS offset (elems)

  #define LDSA_(buf, half) (lds + (((buf) << 1) + (half)) * 8192)
  #define LDSB_(buf, half) (lds + 32768 + (((buf) << 1) + (half)) * (NB * 4096))
  #define KOFFA(h, t) ((size_t)(h) * 128 * K + (size_t)(t) * 64)
  #define KOFFB(h, t) ((size_t)(h) * (64 * NB) * K + (size_t)(t) * 64)
  #define STAGE_A(srcbase, ldshalf, koff) do {                                        \
    __builtin_amdgcn_global_load_lds((gvoid_t*)((srcbase) + (koff)),                  \
        (svoid_t*)((ldshalf) + wOff), 16, 0, 0);                                      \
    __builtin_amdgcn_global_load_lds((gvoid_t*)((srcbase) + (koff) + K64),            \
        (svoid_t*)((ldshalf) + wOff + 4096), 16, 0, 0);                               \
  } while (0)
  #define STAGE_B(srcbase, ldshalf, koff) do {                                        \
    _Pragma("unroll")                                                                 \
    for (int j_ = 0; j_ < NB; ++j_)                                                   \
      __builtin_amdgcn_global_load_lds(                                               \
          (gvoid_t*)((srcbase) + (koff) + (size_t)j_ * K64),                          \
          (svoid_t*)((ldshalf) + wOff + j_ * 4096), 16, 0, 0);                        \
  } while (0)

  const int rowA = (wr * 64 + l16) * 64;          // within half-tile, elems
  const int rowB = (wc * (16 * NB) + l16) * 64;
  const int xo0 = ((quad)     ^ (l16 & 7)) * 8;   // ks=0 chunk
  const int xo1 = ((4 + quad) ^ (l16 & 7)) * 8;   // ks=1 chunk

  floatx4 acc[8][2 * NB] = {};
  shortx8 Afr[4][2];
  shortx8 Bfr[2 * NB][2];

  STAGE_A(a_src, LDSA_(0, 0), KOFFA(0, 0));
  STAGE_B(b_src, LDSB_(0, 0), KOFFB(0, 0));
  STAGE_B(b_src, LDSB_(0, 1), KOFFB(1, 0));
  STAGE_A(a_src, LDSA_(0, 1), KOFFA(1, 0));
  if (NT > 1) {
    STAGE_A(a_src, LDSA_(1, 0), KOFFA(0, 1));
    STAGE_B(b_src, LDSB_(1, 0), KOFFB(0, 1));
    STAGE_B(b_src, LDSB_(1, 1), KOFFB(1, 1));
  }

  for (int t = 0; t < NT; ++t) {
    const int buf = t & 1;
    unsigned short* sA0 = LDSA_(buf, 0);
    unsigned short* sA1 = LDSA_(buf, 1);
    unsigned short* sB0 = LDSB_(buf, 0);
    unsigned short* sB1 = LDSB_(buf, 1);

    // ---- phase 0 ----
    if (t == NT - 1) asm volatile("s_waitcnt vmcnt(0)" ::: "memory");
    else if constexpr (NB == 2) asm volatile("s_waitcnt vmcnt(6)" ::: "memory");
    else                        asm volatile("s_waitcnt vmcnt(4)" ::: "memory");
    __builtin_amdgcn_s_barrier();
    #pragma unroll
    for (int mi = 0; mi < 4; ++mi) {
      Afr[mi][0] = *(const shortx8*)(sA0 + rowA + mi * 1024 + xo0);
      Afr[mi][1] = *(const shortx8*)(sA0 + rowA + mi * 1024 + xo1);
    }
    #pragma unroll
    for (int ni = 0; ni < NB; ++ni) {
      Bfr[ni][0] = *(const shortx8*)(sB0 + rowB + ni * 1024 + xo0);
      Bfr[ni][1] = *(const shortx8*)(sB0 + rowB + ni * 1024 + xo1);
    }
    if (t + 1 < NT) STAGE_A(a_src, LDSA_(buf ^ 1, 1), KOFFA(1, t + 1));
    asm volatile("s_waitcnt lgkmcnt(0)" ::: "memory");
    __builtin_amdgcn_s_setprio(1);
    #pragma unroll
    for (int ks = 0; ks < 2; ++ks)
      #pragma unroll
      for (int mi = 0; mi < 4; ++mi)
        #pragma unroll
        for (int ni = 0; ni < NB; ++ni)
          acc[mi][ni] = mfma16(Afr[mi][ks], Bfr[ni][ks], acc[mi][ni]);
    __builtin_amdgcn_s_setprio(0);
    __builtin_amdgcn_s_barrier();

    // ---- phase 1 ----
    #pragma unroll
    for (int ni = 0; ni < NB; ++ni) {
      Bfr[NB + ni][0] = *(const shortx8*)(sB1 + rowB + ni * 1024 + xo0);
      Bfr[NB + ni][1] = *(const shortx8*)(sB1 + rowB + ni * 1024 + xo1);
    }
    if (t + 2 < NT) STAGE_A(a_src, LDSA_(buf, 0), KOFFA(0, t + 2));
    __builtin_amdgcn_s_barrier();
    asm volatile("s_waitcnt lgkmcnt(0)" ::: "memory");
    __builtin_amdgcn_s_setprio(1);
    #pragma unroll
    for (int ks = 0; ks < 2; ++ks)
      #pragma unroll
      for (int mi = 0; mi < 4; ++mi)
        #pragma unroll
        for (int ni = 0; ni < NB; ++ni)
          acc[mi][NB + ni] = mfma16(Afr[mi][ks], Bfr[NB + ni][ks], acc[mi][NB + ni]);
    __builtin_amdgcn_s_setprio(0);
    __builtin_amdgcn_s_barrier();

    // ---- phase 2 ----
    #pragma unroll
    for (int mi = 0; mi < 4; ++mi) {
      Afr[mi][0] = *(const shortx8*)(sA1 + rowA + mi * 1024 + xo0);
      Afr[mi][1] = *(const shortx8*)(sA1 + rowA + mi * 1024 + xo1);
    }
    if (t + 2 < NT) STAGE_B(b_src, LDSB_(buf, 0), KOFFB(0, t + 2));
    __builtin_amdgcn_s_barrier();
    asm volatile("s_waitcnt lgkmcnt(0)" ::: "memory");
    __builtin_amdgcn_s_setprio(1);
    #pragma unroll
    for (int ks = 0; ks < 2; ++ks)
      #pragma unroll
      for (int mi = 0; mi < 4; ++mi)
        #pragma unroll
        for (int ni = 0; ni < NB; ++ni)
          acc[4 + mi][NB + ni] = mfma16(Afr[mi][ks], Bfr[NB + ni][ks], acc[4 + mi][NB + ni]);
    __builtin_amdgcn_s_setprio(0);
    __builtin_amdgcn_s_barrier();

    // ---- phase 3 ----
    if (t + 2 < NT) STAGE_B(b_src, LDSB_(buf, 1), KOFFB(1, t + 2));
    __builtin_amdgcn_s_barrier();
    __builtin_amdgcn_s_setprio(1);
    #pragma unroll
    for (int ks = 0; ks < 2; ++ks)
      #pragma unroll
      for (int mi = 0; mi < 4; ++mi)
        #pragma unroll
        for (int ni = 0; ni < NB; ++ni)
          acc[4 + mi][ni] = mfma16(Afr[mi][ks], Bfr[ni][ks], acc[4 + mi][ni]);
    __builtin_amdgcn_s_setprio(0);
    __builtin_amdgcn_s_barrier();
  }

  #pragma unroll
  for (int mi = 0; mi < 8; ++mi) {
    const int row = bm + (mi >> 2) * 128 + wr * 64 + (mi & 3) * 16 + quad * 4;
    #pragma unroll
    for (int ni = 0; ni < 2 * NB; ++ni) {
      const int col = bn + (ni / NB) * (64 * NB) + wc * (16 * NB) + (ni % NB) * 16 + l16;
      const float bv = bias[col];
      #pragma unroll
      for (int r = 0; r < 4; ++r) {
        float v = acc[mi][ni][r] + bv;
        if (c_bf16)
          ((unsigned short*)Cout)[(size_t)(row + r) * N + col] = f2bf_hw(v);
        else
          ((float*)Cout)[(size_t)(row + r) * N + col] = v;
      }
    }
  }
  #undef LDSA_
  #undef LDSB_
  #undef KOFFA
  #undef KOFFB
  #undef STAGE_A
  #undef STAGE_B
}

// ---------------- flash attention, GQA, causal — paired blocks + split-K -------
// R4 structure (proven 84us) + split V-wait: stage K then V; vmcnt(4) -> K
// visible for QK while V still in flight; vmcnt(0)+barrier only before PV.
// grid (16, N_HEADS, B) = 512 blocks x 512 threads; wave = (split, rowgroup).
// 73728 B LDS -> 2 blocks/CU = 16 waves/CU = 4 waves/SIMD.
__global__ __launch_bounds__(512, 4) void attn_kernel(
    const unsigned short* __restrict__ qkv,   // (B*T, 3072) bf16 (for Q)
    const unsigned short* __restrict__ kst,   // [b][kvh][d8][t][8]
    const unsigned short* __restrict__ vst,   // [b][kvh][t8][d][8]
    unsigned short* __restrict__ aout)        // (B*T, D_MODEL) bf16
{
  __shared__ __align__(16) unsigned short sK[2][16 * 64 * 8];   // per split [d8][key][8]
  __shared__ __align__(16) unsigned short sV[2][8 * 128 * 8];   // per split [t8][d][8]
  __shared__ __align__(16) unsigned short sP[8][4 * 16 * 8];    // per wave, half-P

  const int tid  = threadIdx.x;
  const int wave = tid >> 6, lane = tid & 63;
  const int split = wave >> 2, g = wave & 3;
  const int quad = lane >> 4, l16 = lane & 15;
  const int head = blockIdx.y, b = blockIdx.z;
  const int kvh = head >> 2;
  const float cf = 0.08838834764831845f * 1.4426950408889634f;  // scale*log2e
  const float THR = 25.0f;  // defer-max threshold (raw S units)

  const unsigned short* kbase = kst + (size_t)((b * KV_HEADS + kvh) * 16) * 2048 * 8;
  const unsigned short* vbase = vst + (size_t)((b * KV_HEADS + kvh) * 256) * 128 * 8;
  unsigned short* sPw = sP[wave];

  // merge scratch overlays K/V LDS (only used after the kt loop, post-barrier)
  float* mrgO  = (float*)&sK[0][0];   // [g][row16][col128] f32 = 32 KB
  float* mrgML = (float*)&sV[0][0];   // [g][lane][r][{m,l}] f32 = 8 KB

  // per-wave stage of one K/V tile into split-s buffer; K loads FIRST (oldest)
  #define STAGE_KV(sp, kb_) do {                                               \
    _Pragma("unroll")                                                          \
    for (int it_ = 0; it_ < 4; ++it_) {                                        \
      const int c_ = it_ * 4 + g;                                              \
      __builtin_amdgcn_global_load_lds(                                        \
          (gvoid_t*)(kbase + ((size_t)c_ * 2048 + (kb_)) * 8 + lane * 8),      \
          (svoid_t*)(&sK[sp][c_ * 512]), 16, 0, 0);                            \
    }                                                                          \
    const unsigned short* vt_ = vbase + (size_t)((kb_) >> 3) * 128 * 8;        \
    _Pragma("unroll")                                                          \
    for (int it_ = 0; it_ < 4; ++it_) {                                        \
      const int c_ = it_ * 4 + g;                                              \
      __builtin_amdgcn_global_load_lds(                                        \
          (gvoid_t*)(vt_ + c_ * 512 + lane * 8),                               \
          (svoid_t*)(&sV[sp][c_ * 512]), 16, 0, 0);                            \
    }                                                                          \
  } while (0)

  #pragma unroll 1
  for (int half = 0; half < 2; ++half) {
    const int qt = half ? blockIdx.x : (31 - blockIdx.x);
    const int q0 = qt * 64;

    // Q fragments (rowgroup g rows; both splits load the same rows)
    shortx8 qf[4];
    {
      const unsigned short* qp = qkv + (size_t)(b * T_SEQ + q0 + g * 16 + l16) * QKV_N
                                 + head * HEAD_DIM + quad * 8;
      #pragma unroll
      for (int ks = 0; ks < 4; ++ks)
        qf[ks] = *(const shortx8*)(qp + ks * 32);
    }

    float m_i[4], l_i[4];
    #pragma unroll
    for (int r = 0; r < 4; ++r) { m_i[r] = -__builtin_inff(); l_i[r] = 0.f; }
    floatx4 o_acc[8] = {};

    const int J = (qt >> 1) + 1;   // ceil((qt+1)/2)
    for (int j = 0; j < J; ++j) {
      const int kt = 2 * j + split;
      const bool act = (kt <= qt);
      floatx4 s[4] = {};

      __builtin_amdgcn_s_barrier();   // A: prev iteration's LDS reads complete
      if (act) STAGE_KV(split, kt * 64);
      asm volatile("s_waitcnt vmcnt(4)" ::: "memory");  // K written; V in flight
      __builtin_amdgcn_s_barrier();   // B: K tile visible to the split's waves

      if (act) {
        // S = Q K^T for this wave's 16 rows x 64 keys
        __builtin_amdgcn_s_setprio(1);
        #pragma unroll
        for (int ks = 0; ks < 4; ++ks) {
          #pragma unroll
          for (int ct = 0; ct < 4; ++ct) {
            shortx8 kf = *(const shortx8*)&sK[split][((ks * 4 + quad) * 64 + ct * 16 + l16) * 8];
            s[ct] = mfma16(qf[ks], kf, s[ct]);
          }
        }
        __builtin_amdgcn_s_setprio(0);

        // causal mask only on the diagonal tile (wave-uniform branch)
        if (kt == qt) {
          const int qrow = q0 + g * 16 + quad * 4;
          const int kb = kt * 64;
          #pragma unroll
          for (int ct = 0; ct < 4; ++ct) {
            const int kcol = kb + ct * 16 + l16;
            #pragma unroll
            for (int r = 0; r < 4; ++r)
              if (kcol > qrow + r) s[ct][r] = -__builtin_inff();
          }
        }

        // cheap defer-max check; full reduce + rescale only in trigger branch
        float lmx[4];
        bool over = false;
        #pragma unroll
        for (int r = 0; r < 4; ++r) {
          lmx[r] = fmaxf(fmaxf(s[0][r], s[1][r]), fmaxf(s[2][r], s[3][r]));
          over = over || (lmx[r] > m_i[r] + THR);
        }
        if (__ballot(over)) {
          float alpha_r[4];
          #pragma unroll
          for (int r = 0; r < 4; ++r) {
            float m = lmx[r];
            m = fmaxf(m, __shfl_xor(m, 1));
            m = fmaxf(m, __shfl_xor(m, 2));
            m = fmaxf(m, __shfl_xor(m, 4));
            m = fmaxf(m, __shfl_xor(m, 8));
            const float newm = fmaxf(m_i[r], m);
            alpha_r[r] = exp2f((m_i[r] - newm) * cf);
            m_i[r] = newm;
            l_i[r] *= alpha_r[r];
          }
          #pragma unroll
          for (int nt = 0; nt < 8; ++nt)
            #pragma unroll
            for (int r = 0; r < 4; ++r) o_acc[nt][r] *= alpha_r[r];
        }

        // P = exp2((S - m)*cf); per-lane partial l
        #pragma unroll
        for (int r = 0; r < 4; ++r) {
          const float nmc = m_i[r] * cf;
          float p0 = exp2f(fmaf(s[0][r], cf, -nmc));
          float p1 = exp2f(fmaf(s[1][r], cf, -nmc));
          float p2 = exp2f(fmaf(s[2][r], cf, -nmc));
          float p3 = exp2f(fmaf(s[3][r], cf, -nmc));
          s[0][r] = p0; s[1][r] = p1; s[2][r] = p2; s[3][r] = p3;
          l_i[r] += (p0 + p1) + (p2 + p3);
        }
      }

      asm volatile("s_waitcnt vmcnt(0)" ::: "memory");  // own V writes done
      __builtin_amdgcn_s_barrier();   // C: V tile visible

      if (act) {
        // O += P V, two k-phases through a 1 KB per-wave sP
        #pragma unroll
        for (int c = 0; c < 2; ++c) {
          #pragma unroll
          for (int ctl = 0; ctl < 2; ++ctl) {
            const int ct = c * 2 + ctl;
            #pragma unroll
            for (int r = 0; r < 4; ++r)
              sPw[((ctl * 2 + (l16 >> 3)) * 16 + quad * 4 + r) * 8 + (l16 & 7)] =
                  f2bf_hw(s[ct][r]);
          }
          __asm__ __volatile__("s_waitcnt lgkmcnt(0)" ::: "memory");
          shortx8 pf = *(const shortx8*)&sPw[(quad * 16 + l16) * 8];
          __builtin_amdgcn_s_setprio(1);
          #pragma unroll
          for (int nt = 0; nt < 8; ++nt) {
            shortx8 vf = *(const shortx8*)&sV[split][((c * 4 + quad) * 128 + nt * 16 + l16) * 8];
            o_acc[nt] = mfma16(pf, vf, o_acc[nt]);
          }
          __builtin_amdgcn_s_setprio(0);
        }
      }
    }

    // ---- merge split partials, then epilogue (split0 finalizes) ----
    __builtin_amdgcn_s_barrier();   // all compute reads of K/V LDS done
    if (split == 1) {
      #pragma unroll
      for (int nt = 0; nt < 8; ++nt)
        #pragma unroll
        for (int r = 0; r < 4; ++r)
          mrgO[g * 2048 + (quad * 4 + r) * 128 + nt * 16 + l16] = o_acc[nt][r];
      #pragma unroll
      for (int r = 0; r < 4; ++r) {
        mrgML[(g * 64 + lane) * 8 + r * 2]     = m_i[r];
        mrgML[(g * 64 + lane) * 8 + r * 2 + 1] = l_i[r];
      }
    }
    asm volatile("s_waitcnt lgkmcnt(0)" ::: "memory");
    __builtin_amdgcn_s_barrier();   // partials visible

    if (split == 0) {
      float lm[4], a0[4], a1[4];
      #pragma unroll
      for (int r = 0; r < 4; ++r) {
        const float m1 = mrgML[(g * 64 + lane) * 8 + r * 2];
        const float l1 = mrgML[(g * 64 + lane) * 8 + r * 2 + 1];
        const float M = fmaxf(m_i[r], m1);
        a0[r] = exp2f((m_i[r] - M) * cf);
        a1[r] = exp2f((m1 - M) * cf);
        lm[r] = a0[r] * l_i[r] + a1[r] * l1;
      }
      #pragma unroll
      for (int nt = 0; nt < 8; ++nt)
        #pragma unroll
        for (int r = 0; r < 4; ++r)
          o_acc[nt][r] = a0[r] * o_acc[nt][r]
                       + a1[r] * mrgO[g * 2048 + (quad * 4 + r) * 128 + nt * 16 + l16];

      const int trow = q0 + g * 16 + quad * 4;
      #pragma unroll
      for (int r = 0; r < 4; ++r) {
        float l = lm[r];
        l += __shfl_xor(l, 1);
        l += __shfl_xor(l, 2);
        l += __shfl_xor(l, 4);
        l += __shfl_xor(l, 8);
        const float inv = 1.f / l;
        #pragma unroll
        for (int nt = 0; nt < 8; ++nt) {
          aout[(size_t)(b * T_SEQ + trow + r) * D_MODEL + head * HEAD_DIM + nt * 16 + l16] =
              f2bf_hw(o_acc[nt][r] * inv);
        }
      }
    }
  }
  #undef STAGE_KV
}

extern "C" void kernel_launch(void* const* d_in, const int* in_sizes, int n_in,
                              void* d_out, int out_size, void* d_ws, size_t ws_size,
                              hipStream_t stream) {
  const float* x      = (const float*)d_in[0];
  // d_in[1] = attn_mask (causal; unused)
  const float* qkv_w  = (const float*)d_in[2];
  const float* qkv_b  = (const float*)d_in[3];
  const float* proj_w = (const float*)d_in[4];
  const float* proj_b = (const float*)d_in[5];
  float* out = (float*)d_out;

  char* ws = (char*)d_ws;
  unsigned short* x_bf    = (unsigned short*)(ws);
  unsigned short* qkvw_t  = (unsigned short*)(ws + (size_t)16777216);
  unsigned short* projw_t = (unsigned short*)(ws + (size_t)29360128);
  unsigned short* qkvbuf  = (unsigned short*)(ws + (size_t)37748736);
  unsigned short* vstaged = (unsigned short*)(ws + (size_t)62914560);
  unsigned short* kstaged = qkvw_t;  // safe alias: qkvw_t dead after GEMM1
  unsigned short* attn_out = x_bf;   // safe alias: x_bf dead after GEMM1

  cvt_x<<<(ROWS * D_MODEL / 4 + 255) / 256, 256, 0, stream>>>(x, x_bf, ROWS * D_MODEL / 4);
  transpose_cvt<<<dim3(QKV_N / 32, D_MODEL / 32), dim3(32, 8), 0, stream>>>(qkv_w, qkvw_t, D_MODEL, QKV_N);
  transpose_cvt<<<dim3(D_MODEL / 32, D_MODEL / 32), dim3(32, 8), 0, stream>>>(proj_w, projw_t, D_MODEL, D_MODEL);
  gemm256<2><<<dim3(QKV_N / 256, ROWS / 256), 512, 0, stream>>>(
      x_bf, qkvw_t, qkv_b, (void*)qkvbuf, ROWS, QKV_N, D_MODEL, 1);
  build_kt<<<1024, 256, 0, stream>>>(qkvbuf, kstaged);
  build_vt<<<1024, 256, 0, stream>>>(qkvbuf, vstaged);
  attn_kernel<<<dim3(16, N_HEADS, BATCH), 512, 0, stream>>>(qkvbuf, kstaged, vstaged, attn_out);
  gemm256<1><<<dim3(D_MODEL / 128, ROWS / 256), 512, 0, stream>>>(
      attn_out, projw_t, proj_b, (void*)out, ROWS, D_MODEL, D_MODEL, 0);
}